// Round 2
// baseline (11646.571 us; speedup 1.0000x reference)
//
#include <hip/hip_runtime.h>
#include <hip/hip_bf16.h>

#define TOPK 8

__device__ __forceinline__ float sigmoidf_(float x) {
  return 1.0f / (1.0f + expf(-x));
}

// Swizzled addressing for [64][64] f32 LDS tiles, 4-float chunks:
// phys_chunk = logical_chunk ^ (row & 7).  Keeps every row 16B-aligned
// (b128-capable) while spreading step-1-mod-8 row sets across all banks.
__device__ __forceinline__ float* rc(float* base, int r, int ch) {
  return base + r * 64 + (((ch) ^ (r & 7)) << 2);
}
__device__ __forceinline__ const float* rcc(const float* base, int r, int ch) {
  return base + r * 64 + (((ch) ^ (r & 7)) << 2);
}

// ---------------------------------------------------------------------------
// Kernel 1: per-(b,l) patch graph conv.  grid = 8192, block = 256.
// LDS 54,016 B -> 3 blocks/CU.
// ---------------------------------------------------------------------------
__global__ __launch_bounds__(256, 3) void graphconv_kernel(
    const float* __restrict__ x,        // (256, 64, 2048)
    const float* __restrict__ filters,  // (3, 64, 64)
    float* __restrict__ g)              // (16384, 32, 64)
{
  __shared__ float A[64 * 64];      // xf / Tx2 (swizzled)
  __shared__ float B[64 * 64];      // Gram/sim / Tx1 (swizzled)
  __shared__ float F[64 * 64];      // current filter (linear)
  __shared__ float adjw[64][9];
  __shared__ int   adjidx[64][9];
  __shared__ float sq[64];

  const int tid  = threadIdx.x;
  const int lane = tid & 63;
  const int wv   = tid >> 6;
  const int m = blockIdx.x;
  const int b = m >> 5;
  const int l = m & 31;

  // ---- load xf -> A (swizzled) ----
  {
    const int s   = tid >> 2;
    const int ch0 = (tid & 3) * 4;
    const float* src = x + ((size_t)b * 64 + s) * 2048 + (size_t)l * 64 + ch0 * 4;
    #pragma unroll
    for (int i = 0; i < 4; ++i)
      *(float4*)rc(A, s, ch0 + i) = *(const float4*)(src + i * 4);
  }
  __syncthreads();

  // ---- Gram: strided 4x4 tile (rows pn+16i x rows pk+16t) ----
  const int pn = tid >> 4;   // 0..15
  const int pk = tid & 15;   // 0..15
  {
    float acc[4][4] = {};
    for (int ch = 0; ch < 16; ++ch) {
      float4 av[4], cv[4];
      #pragma unroll
      for (int i = 0; i < 4; ++i) av[i] = *(const float4*)rcc(A, pn + 16 * i, ch);
      #pragma unroll
      for (int t = 0; t < 4; ++t) cv[t] = *(const float4*)rcc(A, pk + 16 * t, ch);
      #pragma unroll
      for (int i = 0; i < 4; ++i)
        #pragma unroll
        for (int t = 0; t < 4; ++t) {
          acc[i][t] += av[i].x * cv[t].x;
          acc[i][t] += av[i].y * cv[t].y;
          acc[i][t] += av[i].z * cv[t].z;
          acc[i][t] += av[i].w * cv[t].w;
        }
    }
    #pragma unroll
    for (int i = 0; i < 4; ++i)
      #pragma unroll
      for (int t = 0; t < 4; ++t) {
        const int n = pn + 16 * i, k = pk + 16 * t;
        B[n * 64 + (((k >> 2) ^ (n & 7)) << 2) + (k & 3)] = acc[i][t];
      }
  }
  __syncthreads();
  if (tid < 64) {
    const int n = tid;
    sq[n] = B[n * 64 + (((n >> 2) ^ (n & 7)) << 2) + (n & 3)];
  }
  __syncthreads();

  // ---- sim = exp(-max(d2,0)) in place (b128, logical col recovered) ----
  for (int e = tid; e < 1024; e += 256) {
    const int n = e >> 4, pc = e & 15;
    float4 v = *(float4*)(B + n * 64 + pc * 4);
    const int lc = (pc ^ (n & 7)) << 2;
    v.x = expf(-fmaxf(sq[n] + sq[lc + 0] - 2.0f * v.x, 0.0f));
    v.y = expf(-fmaxf(sq[n] + sq[lc + 1] - 2.0f * v.y, 0.0f));
    v.z = expf(-fmaxf(sq[n] + sq[lc + 2] - 2.0f * v.z, 0.0f));
    v.w = expf(-fmaxf(sq[n] + sq[lc + 3] - 2.0f * v.w, 0.0f));
    *(float4*)(B + n * 64 + pc * 4) = v;
  }
  __syncthreads();

  // ---- top-8: wave 0 (lane = row, register insertion); waves 1-3 load F0 ----
  if (wv == 0) {
    float lv[TOPK]; int li[TOPK];
    #pragma unroll
    for (int j = 0; j < TOPK; ++j) { lv[j] = -1.0f; li[j] = 1 << 20; }
    for (int pc = 0; pc < 16; ++pc) {
      float4 v4 = *(const float4*)(B + lane * 64 + pc * 4);
      const int lc = (pc ^ (lane & 7)) << 2;
      float cand[4] = {v4.x, v4.y, v4.z, v4.w};
      #pragma unroll
      for (int t = 0; t < 4; ++t) {
        float cv = cand[t]; int ci = lc + t;
        #pragma unroll
        for (int s = 0; s < TOPK; ++s) {
          const bool better = (cv > lv[s]) || (cv == lv[s] && ci < li[s]);
          const float tv = lv[s]; const int ti = li[s];
          lv[s] = better ? cv : tv;  li[s] = better ? ci : ti;
          cv    = better ? tv : cv;  ci    = better ? ti : ci;
        }
      }
    }
    #pragma unroll
    for (int j = 0; j < TOPK; ++j) { adjw[lane][j] = lv[j]; adjidx[lane][j] = li[j]; }
  } else {
    for (int e = tid - 64; e < 1024; e += 192)
      ((float4*)F)[e] = ((const float4*)filters)[e];
  }
  __syncthreads();

  // ---- Chebyshev: acc over n rows pn+16i, h cols h0..h0+3 ----
  float acc[4][4] = {};
  const int h0 = pk * 4;

  auto gemm_phase = [&](const float* T) {
    for (int ch = 0; ch < 16; ++ch) {
      float4 av[4];
      #pragma unroll
      for (int i = 0; i < 4; ++i) av[i] = *(const float4*)rcc(T, pn + 16 * i, ch);
      #pragma unroll
      for (int kk = 0; kk < 4; ++kk) {
        const float4 f = *(const float4*)(F + (ch * 4 + kk) * 64 + h0);
        #pragma unroll
        for (int i = 0; i < 4; ++i) {
          const float a = (kk == 0) ? av[i].x : (kk == 1) ? av[i].y
                        : (kk == 2) ? av[i].z : av[i].w;
          acc[i][0] += a * f.x;
          acc[i][1] += a * f.y;
          acc[i][2] += a * f.z;
          acc[i][3] += a * f.w;
        }
      }
    }
  };

  const int sn  = tid >> 2;          // sparse phase: row
  const int jc0 = (tid & 3) * 4;     // sparse phase: 4 logical chunks

  auto sparse_gather = [&](const float* S, float o4[4][4]) {
    #pragma unroll
    for (int c = 0; c < 4; ++c)
      o4[c][0] = o4[c][1] = o4[c][2] = o4[c][3] = 0.0f;
    #pragma unroll
    for (int s = 0; s < TOPK; ++s) {
      const float w = adjw[sn][s];
      const int  kk = adjidx[sn][s];
      #pragma unroll
      for (int c = 0; c < 4; ++c) {
        const float4 v = *(const float4*)rcc(S, kk, jc0 + c);
        o4[c][0] += w * v.x; o4[c][1] += w * v.y;
        o4[c][2] += w * v.z; o4[c][3] += w * v.w;
      }
    }
  };

  gemm_phase(A);                 // Tx0 @ F0
  __syncthreads();
  {                              // F1 load; Tx1 = adj @ xf -> B
    for (int e = tid; e < 1024; e += 256)
      ((float4*)F)[e] = ((const float4*)(filters + 4096))[e];
    float o4[4][4];
    sparse_gather(A, o4);
    #pragma unroll
    for (int c = 0; c < 4; ++c)
      *(float4*)rc(B, sn, jc0 + c) =
          make_float4(o4[c][0], o4[c][1], o4[c][2], o4[c][3]);
  }
  __syncthreads();
  gemm_phase(B);                 // Tx1 @ F1
  __syncthreads();
  {                              // F2 load; Tx2 = 2*adj@Tx1 - Tx0 -> A
    for (int e = tid; e < 1024; e += 256)
      ((float4*)F)[e] = ((const float4*)(filters + 8192))[e];
    float o4[4][4];
    sparse_gather(B, o4);
    #pragma unroll
    for (int c = 0; c < 4; ++c) {
      const float4 t0 = *(const float4*)rcc(A, sn, jc0 + c);
      float4 t2;
      t2.x = 2.0f * o4[c][0] - t0.x;
      t2.y = 2.0f * o4[c][1] - t0.y;
      t2.z = 2.0f * o4[c][2] - t0.z;
      t2.w = 2.0f * o4[c][3] - t0.w;
      *(float4*)rc(A, sn, jc0 + c) = t2;
    }
  }
  __syncthreads();
  gemm_phase(A);                 // Tx2 @ F2

  // ---- store g ----
  #pragma unroll
  for (int i = 0; i < 4; ++i) {
    const float4 v = make_float4(acc[i][0], acc[i][1], acc[i][2], acc[i][3]);
    *(float4*)(g + (((size_t)(b * 64 + pn + 16 * i)) * 32 + l) * 64 + h0) = v;
  }
}

// ---------------------------------------------------------------------------
// Kernel 2: GRU (32 steps) + fused FC.  grid = 256, block = 512.
// Thread tile = 4h x 2seq. LDS 152,320 B -> 1 block/CU, 2 waves/SIMD.
// W stored swizzled (phys_chunk = ch ^ ((row>>2)&7)) for b128 reads;
// X double-buffered with register prefetch of step l+1.
// ---------------------------------------------------------------------------
__global__ __launch_bounds__(512, 2) void gru_fc_kernel(
    const float* __restrict__ gg,    // (16384, 32, 64)
    const float* __restrict__ w_ih,  // (192, 64)
    const float* __restrict__ w_hh,  // (192, 64)
    const float* __restrict__ b_ih,
    const float* __restrict__ b_hh,
    const float* __restrict__ fc_w,  // (131072) = n*2048 + l*64 + h
    const float* __restrict__ fc_b,
    float* __restrict__ out)         // (256)
{
  __shared__ float Wi[192 * 64];
  __shared__ float Wh[192 * 64];
  __shared__ float X[2][64][68];
  __shared__ float H[64][68];
  __shared__ float bi[192], bh[192];
  __shared__ float red[64];

  const int tid = threadIdx.x;
  const int blk = blockIdx.x;

  // stage W swizzled
  for (int e = tid; e < 3072; e += 512) {
    const int r = e >> 4, ch = e & 15;
    const int po = r * 64 + ((ch ^ ((r >> 2) & 7)) << 2);
    *(float4*)(Wi + po) = *(const float4*)(w_ih + r * 64 + ch * 4);
    *(float4*)(Wh + po) = *(const float4*)(w_hh + r * 64 + ch * 4);
  }
  if (tid < 192) { bi[tid] = b_ih[tid]; bh[tid] = b_hh[tid]; }
  for (int e = tid; e < 64 * 68; e += 512) (&H[0][0])[e] = 0.0f;
  // stage X[0]
  {
    const int s = tid >> 3, c = (tid & 7) * 8;
    const float* src = gg + (((size_t)(blk * 64 + s)) * 32 + 0) * 64 + c;
    *(float4*)&X[0][s][c]     = *(const float4*)(src);
    *(float4*)&X[0][s][c + 4] = *(const float4*)(src + 4);
  }
  __syncthreads();

  const int hg = tid & 15;
  const int sg = tid >> 4;     // 0..31
  const int h0 = hg * 4;
  const int s0 = sg * 2;
  const int swzk = hg & 7;     // W swizzle key for rows h0..h0+3 (+64,+128)

  float fcp[2] = {0.0f, 0.0f};
  int cur = 0;

  const int ps = tid >> 3, pc = (tid & 7) * 8;   // X staging mapping

  for (int lstep = 0; lstep < 32; ++lstep) {
    // prefetch next xt into registers (hidden under this step's compute)
    float4 pf0, pf1;
    if (lstep + 1 < 32) {
      const float* src =
          gg + (((size_t)(blk * 64 + ps)) * 32 + (lstep + 1)) * 64 + pc;
      pf0 = *(const float4*)(src);
      pf1 = *(const float4*)(src + 4);
    }

    float arz0[4][2] = {}, arz1[4][2] = {}, ain[4][2] = {}, ahn[4][2] = {};
    #pragma unroll 2
    for (int ch = 0; ch < 16; ++ch) {
      float4 xv[2], hv[2];
      #pragma unroll
      for (int js = 0; js < 2; ++js) {
        xv[js] = *(const float4*)&X[cur][s0 + js][ch * 4];
        hv[js] = *(const float4*)&H[s0 + js][ch * 4];
      }
      const int swz = (ch ^ swzk) << 2;
      #pragma unroll
      for (int i = 0; i < 4; ++i) {
        const int h = h0 + i;
        const float4 wir = *(const float4*)(Wi + h * 64 + swz);
        const float4 whr = *(const float4*)(Wh + h * 64 + swz);
        const float4 wiz = *(const float4*)(Wi + (64 + h) * 64 + swz);
        const float4 whz = *(const float4*)(Wh + (64 + h) * 64 + swz);
        const float4 win = *(const float4*)(Wi + (128 + h) * 64 + swz);
        const float4 whn = *(const float4*)(Wh + (128 + h) * 64 + swz);
        #pragma unroll
        for (int js = 0; js < 2; ++js) {
          arz0[i][js] += wir.x * xv[js].x; arz0[i][js] += whr.x * hv[js].x;
          arz0[i][js] += wir.y * xv[js].y; arz0[i][js] += whr.y * hv[js].y;
          arz0[i][js] += wir.z * xv[js].z; arz0[i][js] += whr.z * hv[js].z;
          arz0[i][js] += wir.w * xv[js].w; arz0[i][js] += whr.w * hv[js].w;
          arz1[i][js] += wiz.x * xv[js].x; arz1[i][js] += whz.x * hv[js].x;
          arz1[i][js] += wiz.y * xv[js].y; arz1[i][js] += whz.y * hv[js].y;
          arz1[i][js] += wiz.z * xv[js].z; arz1[i][js] += whz.z * hv[js].z;
          arz1[i][js] += wiz.w * xv[js].w; arz1[i][js] += whz.w * hv[js].w;
          ain[i][js]  += win.x * xv[js].x; ahn[i][js]  += whn.x * hv[js].x;
          ain[i][js]  += win.y * xv[js].y; ahn[i][js]  += whn.y * hv[js].y;
          ain[i][js]  += win.z * xv[js].z; ahn[i][js]  += whn.z * hv[js].z;
          ain[i][js]  += win.w * xv[js].w; ahn[i][js]  += whn.w * hv[js].w;
        }
      }
    }

    float hnew[4][2];
    #pragma unroll
    for (int i = 0; i < 4; ++i) {
      const int h = h0 + i;
      const float br   = bi[h] + bh[h];
      const float bz   = bi[64 + h] + bh[64 + h];
      const float bin_ = bi[128 + h];
      const float bhn_ = bh[128 + h];
      #pragma unroll
      for (int js = 0; js < 2; ++js) {
        const float r  = sigmoidf_(arz0[i][js] + br);
        const float z  = sigmoidf_(arz1[i][js] + bz);
        const float nv = tanhf(ain[i][js] + bin_ + r * (ahn[i][js] + bhn_));
        const float hold = H[s0 + js][h];
        const float hv = (1.0f - z) * nv + z * hold;
        hnew[i][js] = hv;
        fcp[js] += hv * fc_w[(size_t)(s0 + js) * 2048 + (size_t)lstep * 64 + h];
      }
    }
    __syncthreads();   // all reads of H / X[cur] done
    #pragma unroll
    for (int i = 0; i < 4; ++i)
      #pragma unroll
      for (int js = 0; js < 2; ++js)
        H[s0 + js][h0 + i] = hnew[i][js];
    if (lstep + 1 < 32) {
      *(float4*)&X[cur ^ 1][ps][pc]     = pf0;
      *(float4*)&X[cur ^ 1][ps][pc + 4] = pf1;
    }
    cur ^= 1;
    __syncthreads();   // writes visible
  }

  // ---- FC reduce ----
  #pragma unroll
  for (int js = 0; js < 2; ++js) {
    float v = fcp[js];
    v += __shfl_xor(v, 1); v += __shfl_xor(v, 2);
    v += __shfl_xor(v, 4); v += __shfl_xor(v, 8);
    if (hg == 0) red[s0 + js] = v;
  }
  __syncthreads();
  if (tid < 64) {
    float v = red[tid];
    v += __shfl_xor(v, 1);  v += __shfl_xor(v, 2);
    v += __shfl_xor(v, 4);  v += __shfl_xor(v, 8);
    v += __shfl_xor(v, 16); v += __shfl_xor(v, 32);
    if (tid == 0) out[blk] = v + fc_b[0];
  }
}

// ---------------------------------------------------------------------------
extern "C" void kernel_launch(void* const* d_in, const int* in_sizes, int n_in,
                              void* d_out, int out_size, void* d_ws, size_t ws_size,
                              hipStream_t stream) {
  (void)in_sizes; (void)n_in; (void)out_size; (void)ws_size;
  const float* x       = (const float*)d_in[0];
  const float* filters = (const float*)d_in[1];
  const float* w_ih    = (const float*)d_in[2];
  const float* w_hh    = (const float*)d_in[3];
  const float* b_ih    = (const float*)d_in[4];
  const float* b_hh    = (const float*)d_in[5];
  const float* fc_w    = (const float*)d_in[6];
  const float* fc_b    = (const float*)d_in[7];
  float* out = (float*)d_out;
  float* g   = (float*)d_ws;   // 16384*32*64 f32 = 134 MB

  graphconv_kernel<<<8192, 256, 0, stream>>>(x, filters, g);
  gru_fc_kernel<<<256, 512, 0, stream>>>(g, w_ih, w_hh, b_ih, b_hh,
                                         fc_w, fc_b, out);
}

// Round 3
// 1050.083 us; speedup vs baseline: 11.0911x; 11.0911x over previous
//
#include <hip/hip_runtime.h>
#include <hip/hip_bf16.h>

__device__ __forceinline__ float sigmoidf_(float x) {
  return 1.0f / (1.0f + expf(-x));
}

#define FMA4(ACC, S, V)                                                        \
  ACC.x += (S) * (V).x; ACC.y += (S) * (V).y;                                  \
  ACC.z += (S) * (V).z; ACC.w += (S) * (V).w;

#define DOT4(ACC, AV, CV)                                                      \
  ACC += (AV).x * (CV).x; ACC += (AV).y * (CV).y;                              \
  ACC += (AV).z * (CV).z; ACC += (AV).w * (CV).w;

// ---------------------------------------------------------------------------
// Kernel 1: per-(b,l) patch graph conv.  grid = 8192, block = 256.
// LDS = 54,016 B -> target 3 blocks/CU.  All LDS access b128, <=2-way banks.
// ---------------------------------------------------------------------------
__global__ __launch_bounds__(256, 3) void graphconv_kernel(
    const float* __restrict__ x,        // (256, 64, 2048)
    const float* __restrict__ filters,  // (3, 64, 64)
    float* __restrict__ g)              // (16384, 32, 64)
{
  __shared__ float A[64][68];                 // xf / Tx2
  __shared__ float B[64][68];                 // Gram / sim / Tx1
  __shared__ float F[64 * 64];                // current filter (linear)
  __shared__ float adjw[64][8];
  __shared__ unsigned long long adjp[64];     // 8 packed byte-indices per row
  __shared__ float sq[64];

  const int tid = threadIdx.x;
  const int m  = blockIdx.x;
  const int bb = m >> 5;
  const int l  = m & 31;

  // ---- stage xf -> A (coalesced global, 2-way LDS writes) ----
  {
    const int s  = tid >> 2;
    const int c0 = (tid & 3) * 16;
    const float* src = x + ((size_t)bb * 64 + s) * 2048 + l * 64 + c0;
    const float4 v0 = *(const float4*)(src + 0);
    const float4 v1 = *(const float4*)(src + 4);
    const float4 v2 = *(const float4*)(src + 8);
    const float4 v3 = *(const float4*)(src + 12);
    *(float4*)&A[s][c0 + 0]  = v0;
    *(float4*)&A[s][c0 + 4]  = v1;
    *(float4*)&A[s][c0 + 8]  = v2;
    *(float4*)&A[s][c0 + 12] = v3;
  }
  __syncthreads();

  const int pn = tid >> 4;   // 0..15
  const int pk = tid & 15;   // 0..15
  const int h0 = pk * 4;

  // ---- Gram: tile rows {pn+16i} x rows {pk+16t} -> B ----
  {
    float4 acc0 = {0.f,0.f,0.f,0.f}, acc1 = acc0, acc2 = acc0, acc3 = acc0;
    #pragma unroll 4
    for (int ch = 0; ch < 16; ++ch) {
      const float4 av0 = *(const float4*)&A[pn +  0][ch * 4];
      const float4 av1 = *(const float4*)&A[pn + 16][ch * 4];
      const float4 av2 = *(const float4*)&A[pn + 32][ch * 4];
      const float4 av3 = *(const float4*)&A[pn + 48][ch * 4];
      const float4 cv0 = *(const float4*)&A[pk +  0][ch * 4];
      const float4 cv1 = *(const float4*)&A[pk + 16][ch * 4];
      const float4 cv2 = *(const float4*)&A[pk + 32][ch * 4];
      const float4 cv3 = *(const float4*)&A[pk + 48][ch * 4];
      DOT4(acc0.x, av0, cv0) DOT4(acc0.y, av0, cv1)
      DOT4(acc0.z, av0, cv2) DOT4(acc0.w, av0, cv3)
      DOT4(acc1.x, av1, cv0) DOT4(acc1.y, av1, cv1)
      DOT4(acc1.z, av1, cv2) DOT4(acc1.w, av1, cv3)
      DOT4(acc2.x, av2, cv0) DOT4(acc2.y, av2, cv1)
      DOT4(acc2.z, av2, cv2) DOT4(acc2.w, av2, cv3)
      DOT4(acc3.x, av3, cv0) DOT4(acc3.y, av3, cv1)
      DOT4(acc3.z, av3, cv2) DOT4(acc3.w, av3, cv3)
    }
    B[pn +  0][pk +  0] = acc0.x; B[pn +  0][pk + 16] = acc0.y;
    B[pn +  0][pk + 32] = acc0.z; B[pn +  0][pk + 48] = acc0.w;
    B[pn + 16][pk +  0] = acc1.x; B[pn + 16][pk + 16] = acc1.y;
    B[pn + 16][pk + 32] = acc1.z; B[pn + 16][pk + 48] = acc1.w;
    B[pn + 32][pk +  0] = acc2.x; B[pn + 32][pk + 16] = acc2.y;
    B[pn + 32][pk + 32] = acc2.z; B[pn + 32][pk + 48] = acc2.w;
    B[pn + 48][pk +  0] = acc3.x; B[pn + 48][pk + 16] = acc3.y;
    B[pn + 48][pk + 32] = acc3.z; B[pn + 48][pk + 48] = acc3.w;
  }
  __syncthreads();
  if (tid < 64) sq[tid] = B[tid][tid];
  __syncthreads();

  // ---- sim = exp(-max(d2,0)) in place; n = lane (2-way banks) ----
  #pragma unroll
  for (int it = 0; it < 4; ++it) {
    const int e  = tid + it * 256;
    const int n  = e & 63;
    const int pc = e >> 6;
    float4 v = *(const float4*)&B[n][pc * 4];
    const float sn_ = sq[n];
    v.x = expf(-fmaxf(sn_ + sq[pc * 4 + 0] - 2.0f * v.x, 0.0f));
    v.y = expf(-fmaxf(sn_ + sq[pc * 4 + 1] - 2.0f * v.y, 0.0f));
    v.z = expf(-fmaxf(sn_ + sq[pc * 4 + 2] - 2.0f * v.z, 0.0f));
    v.w = expf(-fmaxf(sn_ + sq[pc * 4 + 3] - 2.0f * v.w, 0.0f));
    *(float4*)&B[n][pc * 4] = v;
  }
  __syncthreads();

  // ---- top-8: wave0 register insertion (lane = row); waves 1-3 load F0 ----
#define INSERT(CV, CI)                                                        \
  {                                                                           \
    float cv = (CV); int ci = (CI);                                           \
    _Pragma("unroll")                                                         \
    for (int s_ = 0; s_ < 8; ++s_) {                                          \
      const bool bt = cv > lv[s_];                                            \
      const float tv = lv[s_]; const int ti = li[s_];                         \
      lv[s_] = bt ? cv : tv;  li[s_] = bt ? ci : ti;                          \
      cv     = bt ? tv : cv;  ci     = bt ? ti : ci;                          \
    }                                                                         \
  }
  if (tid < 64) {
    float lv[8]; int li[8];
    #pragma unroll
    for (int j = 0; j < 8; ++j) { lv[j] = -1.0f; li[j] = 0; }
    #pragma unroll 4
    for (int pc = 0; pc < 16; ++pc) {
      const float4 v = *(const float4*)&B[tid][pc * 4];
      INSERT(v.x, pc * 4 + 0)
      INSERT(v.y, pc * 4 + 1)
      INSERT(v.z, pc * 4 + 2)
      INSERT(v.w, pc * 4 + 3)
    }
    unsigned long long p = 0ull;
    #pragma unroll
    for (int j = 0; j < 8; ++j) {
      adjw[tid][j] = lv[j];
      p |= ((unsigned long long)(unsigned)li[j]) << (8 * j);
    }
    adjp[tid] = p;
  } else {
    for (int e = tid - 64; e < 1024; e += 192)
      ((float4*)F)[e] = ((const float4*)filters)[e];
  }
  __syncthreads();

  // ---- Chebyshev ----
  float4 facc0 = {0.f,0.f,0.f,0.f}, facc1 = facc0, facc2 = facc0, facc3 = facc0;

#define GEMM_PHASE(TILE)                                                      \
  {                                                                           \
    _Pragma("unroll 4")                                                       \
    for (int ch = 0; ch < 16; ++ch) {                                         \
      const float4 av0 = *(const float4*)&TILE[pn +  0][ch * 4];              \
      const float4 av1 = *(const float4*)&TILE[pn + 16][ch * 4];              \
      const float4 av2 = *(const float4*)&TILE[pn + 32][ch * 4];              \
      const float4 av3 = *(const float4*)&TILE[pn + 48][ch * 4];              \
      const float4 f0 = *(const float4*)(F + (ch * 4 + 0) * 64 + h0);         \
      const float4 f1 = *(const float4*)(F + (ch * 4 + 1) * 64 + h0);         \
      const float4 f2 = *(const float4*)(F + (ch * 4 + 2) * 64 + h0);         \
      const float4 f3 = *(const float4*)(F + (ch * 4 + 3) * 64 + h0);         \
      FMA4(facc0, av0.x, f0) FMA4(facc0, av0.y, f1)                           \
      FMA4(facc0, av0.z, f2) FMA4(facc0, av0.w, f3)                           \
      FMA4(facc1, av1.x, f0) FMA4(facc1, av1.y, f1)                           \
      FMA4(facc1, av1.z, f2) FMA4(facc1, av1.w, f3)                           \
      FMA4(facc2, av2.x, f0) FMA4(facc2, av2.y, f1)                           \
      FMA4(facc2, av2.z, f2) FMA4(facc2, av2.w, f3)                           \
      FMA4(facc3, av3.x, f0) FMA4(facc3, av3.y, f1)                           \
      FMA4(facc3, av3.z, f2) FMA4(facc3, av3.w, f3)                           \
    }                                                                         \
  }

  const int sn = tid >> 2;
  const int jb = (tid & 3) * 16;

#define SPARSE_GATHER(SRC)                                                    \
  {                                                                           \
    const unsigned long long p_ = adjp[sn];                                   \
    _Pragma("unroll")                                                         \
    for (int s_ = 0; s_ < 8; ++s_) {                                          \
      const float w_ = adjw[sn][s_];                                          \
      const int kk_ = (int)((p_ >> (8 * s_)) & 63);                           \
      const float4 q0 = *(const float4*)&SRC[kk_][jb + 0];                    \
      const float4 q1 = *(const float4*)&SRC[kk_][jb + 4];                    \
      const float4 q2 = *(const float4*)&SRC[kk_][jb + 8];                    \
      const float4 q3 = *(const float4*)&SRC[kk_][jb + 12];                   \
      FMA4(o0, w_, q0) FMA4(o1, w_, q1) FMA4(o2, w_, q2) FMA4(o3, w_, q3)     \
    }                                                                         \
  }

  GEMM_PHASE(A)                // acc += Tx0 @ F0
  __syncthreads();
  {                            // F1 load; Tx1 = adj @ xf -> B
    for (int e = tid; e < 1024; e += 256)
      ((float4*)F)[e] = ((const float4*)(filters + 4096))[e];
    float4 o0 = {0.f,0.f,0.f,0.f}, o1 = o0, o2 = o0, o3 = o0;
    SPARSE_GATHER(A)
    *(float4*)&B[sn][jb + 0]  = o0;
    *(float4*)&B[sn][jb + 4]  = o1;
    *(float4*)&B[sn][jb + 8]  = o2;
    *(float4*)&B[sn][jb + 12] = o3;
  }
  __syncthreads();
  GEMM_PHASE(B)                // acc += Tx1 @ F1
  __syncthreads();
  {                            // F2 load; Tx2 = 2*adj@Tx1 - Tx0 -> A
    for (int e = tid; e < 1024; e += 256)
      ((float4*)F)[e] = ((const float4*)(filters + 8192))[e];
    float4 o0 = {0.f,0.f,0.f,0.f}, o1 = o0, o2 = o0, o3 = o0;
    SPARSE_GATHER(B)
    const float4 t0 = *(const float4*)&A[sn][jb + 0];
    const float4 t1 = *(const float4*)&A[sn][jb + 4];
    const float4 t2 = *(const float4*)&A[sn][jb + 8];
    const float4 t3 = *(const float4*)&A[sn][jb + 12];
    float4 r0, r1, r2, r3;
    r0.x = 2.0f*o0.x - t0.x; r0.y = 2.0f*o0.y - t0.y;
    r0.z = 2.0f*o0.z - t0.z; r0.w = 2.0f*o0.w - t0.w;
    r1.x = 2.0f*o1.x - t1.x; r1.y = 2.0f*o1.y - t1.y;
    r1.z = 2.0f*o1.z - t1.z; r1.w = 2.0f*o1.w - t1.w;
    r2.x = 2.0f*o2.x - t2.x; r2.y = 2.0f*o2.y - t2.y;
    r2.z = 2.0f*o2.z - t2.z; r2.w = 2.0f*o2.w - t2.w;
    r3.x = 2.0f*o3.x - t3.x; r3.y = 2.0f*o3.y - t3.y;
    r3.z = 2.0f*o3.z - t3.z; r3.w = 2.0f*o3.w - t3.w;
    *(float4*)&A[sn][jb + 0]  = r0;
    *(float4*)&A[sn][jb + 4]  = r1;
    *(float4*)&A[sn][jb + 8]  = r2;
    *(float4*)&A[sn][jb + 12] = r3;
  }
  __syncthreads();
  GEMM_PHASE(A)                // acc += Tx2 @ F2

  // ---- store g: seq = bb*64 + n; idx = seq*2048 + l*64 + h ----
  *(float4*)(g + ((size_t)(bb * 64 + pn +  0)) * 2048 + l * 64 + h0) = facc0;
  *(float4*)(g + ((size_t)(bb * 64 + pn + 16)) * 2048 + l * 64 + h0) = facc1;
  *(float4*)(g + ((size_t)(bb * 64 + pn + 32)) * 2048 + l * 64 + h0) = facc2;
  *(float4*)(g + ((size_t)(bb * 64 + pn + 48)) * 2048 + l * 64 + h0) = facc3;
}

// ---------------------------------------------------------------------------
// Kernel 2: GRU (32 steps) + fused FC.  grid = 256, block = 256.
// Transposed-W LDS layout: WT[k][gate*64+h], 16B-aligned rows of 196 floats.
// All inner-loop LDS reads are broadcast or 2-way.  LDS 154,368 B.
// ---------------------------------------------------------------------------
__global__ __launch_bounds__(256, 1) void gru_fc_kernel(
    const float* __restrict__ gg,    // (16384, 2048) = seq-major
    const float* __restrict__ w_ih,  // (192, 64)
    const float* __restrict__ w_hh,  // (192, 64)
    const float* __restrict__ b_ih,
    const float* __restrict__ b_hh,
    const float* __restrict__ fc_w,  // (131072) = n*2048 + l*64 + h
    const float* __restrict__ fc_b,
    float* __restrict__ out)         // (256)
{
  __shared__ float WTI[64][196];
  __shared__ float WTH[64][196];
  __shared__ float X[2][64][68];
  __shared__ float H[64][68];
  __shared__ float red[64];

  const int tid = threadIdx.x;
  const int blk = blockIdx.x;

  // stage W transposed: WT[k][gh] = w[gh][k]
  for (int e = tid; e < 12288; e += 256) {
    const int gh = e >> 6, k = e & 63;
    WTI[k][gh] = w_ih[e];
    WTH[k][gh] = w_hh[e];
  }
  for (int e = tid; e < 64 * 68; e += 256) (&H[0][0])[e] = 0.0f;

  const int ps  = tid >> 2;
  const int pc0 = (tid & 3) * 16;
  {
    const float* src = gg + ((size_t)(blk * 64 + ps)) * 2048 + pc0;  // l = 0
    *(float4*)&X[0][ps][pc0 + 0]  = *(const float4*)(src + 0);
    *(float4*)&X[0][ps][pc0 + 4]  = *(const float4*)(src + 4);
    *(float4*)&X[0][ps][pc0 + 8]  = *(const float4*)(src + 8);
    *(float4*)&X[0][ps][pc0 + 12] = *(const float4*)(src + 12);
  }
  __syncthreads();

  const int hg = tid & 15, sg = tid >> 4;
  const int h0 = hg * 4,  s0 = sg * 4;

  float br_[4], bz_[4], bin_[4], bhn_[4];
  #pragma unroll
  for (int i = 0; i < 4; ++i) {
    br_[i]  = b_ih[h0 + i]       + b_hh[h0 + i];
    bz_[i]  = b_ih[64 + h0 + i]  + b_hh[64 + h0 + i];
    bin_[i] = b_ih[128 + h0 + i];
    bhn_[i] = b_hh[128 + h0 + i];
  }

  float hprev[4][4] = {};              // [i][js]
  float fcp[4] = {0.f, 0.f, 0.f, 0.f};
  int cur = 0;

  for (int lstep = 0; lstep < 32; ++lstep) {
    // early global loads: fc_w slice + next-step x (latency hidden by compute)
    float4 fw[4];
    #pragma unroll
    for (int js = 0; js < 4; ++js)
      fw[js] = *(const float4*)(fc_w + (size_t)(s0 + js) * 2048
                                + lstep * 64 + h0);
    float4 px0, px1, px2, px3;
    if (lstep + 1 < 32) {
      const float* src = gg + ((size_t)(blk * 64 + ps)) * 2048
                         + (lstep + 1) * 64 + pc0;
      px0 = *(const float4*)(src + 0);
      px1 = *(const float4*)(src + 4);
      px2 = *(const float4*)(src + 8);
      px3 = *(const float4*)(src + 12);
    }

    float ar[4][4] = {}, az[4][4] = {}, ain[4][4] = {}, ahn[4][4] = {};
    #pragma unroll 4
    for (int ch = 0; ch < 16; ++ch) {
      float4 xv[4], hv[4];
      #pragma unroll
      for (int js = 0; js < 4; ++js) {
        xv[js] = *(const float4*)&X[cur][s0 + js][ch * 4];
        hv[js] = *(const float4*)&H[s0 + js][ch * 4];
      }
      #pragma unroll
      for (int kk = 0; kk < 4; ++kk) {
        const int k = ch * 4 + kk;
        const float4 wir = *(const float4*)&WTI[k][h0];
        const float4 whr = *(const float4*)&WTH[k][h0];
        const float4 wiz = *(const float4*)&WTI[k][64 + h0];
        const float4 whz = *(const float4*)&WTH[k][64 + h0];
        const float4 win = *(const float4*)&WTI[k][128 + h0];
        const float4 whn = *(const float4*)&WTH[k][128 + h0];
        #pragma unroll
        for (int js = 0; js < 4; ++js) {
          const float xs = (kk == 0) ? xv[js].x : (kk == 1) ? xv[js].y
                         : (kk == 2) ? xv[js].z : xv[js].w;
          const float hs = (kk == 0) ? hv[js].x : (kk == 1) ? hv[js].y
                         : (kk == 2) ? hv[js].z : hv[js].w;
          ar[0][js] += wir.x * xs;  ar[0][js] += whr.x * hs;
          ar[1][js] += wir.y * xs;  ar[1][js] += whr.y * hs;
          ar[2][js] += wir.z * xs;  ar[2][js] += whr.z * hs;
          ar[3][js] += wir.w * xs;  ar[3][js] += whr.w * hs;
          az[0][js] += wiz.x * xs;  az[0][js] += whz.x * hs;
          az[1][js] += wiz.y * xs;  az[1][js] += whz.y * hs;
          az[2][js] += wiz.z * xs;  az[2][js] += whz.z * hs;
          az[3][js] += wiz.w * xs;  az[3][js] += whz.w * hs;
          ain[0][js] += win.x * xs; ahn[0][js] += whn.x * hs;
          ain[1][js] += win.y * xs; ahn[1][js] += whn.y * hs;
          ain[2][js] += win.z * xs; ahn[2][js] += whn.z * hs;
          ain[3][js] += win.w * xs; ahn[3][js] += whn.w * hs;
        }
      }
    }

    #pragma unroll
    for (int i = 0; i < 4; ++i) {
      #pragma unroll
      for (int js = 0; js < 4; ++js) {
        const float r  = sigmoidf_(ar[i][js] + br_[i]);
        const float z  = sigmoidf_(az[i][js] + bz_[i]);
        const float nv = tanhf(ain[i][js] + bin_[i] + r * (ahn[i][js] + bhn_[i]));
        const float hv_ = (1.0f - z) * nv + z * hprev[i][js];
        hprev[i][js] = hv_;
        const float fwv = (i == 0) ? fw[js].x : (i == 1) ? fw[js].y
                        : (i == 2) ? fw[js].z : fw[js].w;
        fcp[js] += hv_ * fwv;
      }
    }
    __syncthreads();   // all LDS reads of H/X[cur] done
    #pragma unroll
    for (int i = 0; i < 4; ++i)
      #pragma unroll
      for (int js = 0; js < 4; ++js)
        H[s0 + js][h0 + i] = hprev[i][js];
    if (lstep + 1 < 32) {
      *(float4*)&X[cur ^ 1][ps][pc0 + 0]  = px0;
      *(float4*)&X[cur ^ 1][ps][pc0 + 4]  = px1;
      *(float4*)&X[cur ^ 1][ps][pc0 + 8]  = px2;
      *(float4*)&X[cur ^ 1][ps][pc0 + 12] = px3;
    }
    cur ^= 1;
    __syncthreads();   // writes visible for next step
  }

  // ---- FC reduce: over hg (16 lanes), then over all 64 seqs ----
  #pragma unroll
  for (int js = 0; js < 4; ++js) {
    float v = fcp[js];
    v += __shfl_xor(v, 1); v += __shfl_xor(v, 2);
    v += __shfl_xor(v, 4); v += __shfl_xor(v, 8);
    if (hg == 0) red[s0 + js] = v;
  }
  __syncthreads();
  if (tid < 64) {
    float v = red[tid];
    v += __shfl_xor(v, 1);  v += __shfl_xor(v, 2);
    v += __shfl_xor(v, 4);  v += __shfl_xor(v, 8);
    v += __shfl_xor(v, 16); v += __shfl_xor(v, 32);
    if (tid == 0) out[blk] = v + fc_b[0];
  }
}

// ---------------------------------------------------------------------------
extern "C" void kernel_launch(void* const* d_in, const int* in_sizes, int n_in,
                              void* d_out, int out_size, void* d_ws, size_t ws_size,
                              hipStream_t stream) {
  (void)in_sizes; (void)n_in; (void)out_size; (void)ws_size;
  const float* x       = (const float*)d_in[0];
  const float* filters = (const float*)d_in[1];
  const float* w_ih    = (const float*)d_in[2];
  const float* w_hh    = (const float*)d_in[3];
  const float* b_ih    = (const float*)d_in[4];
  const float* b_hh    = (const float*)d_in[5];
  const float* fc_w    = (const float*)d_in[6];
  const float* fc_b    = (const float*)d_in[7];
  float* out = (float*)d_out;
  float* g   = (float*)d_ws;   // 16384*2048 f32 = 134 MB

  graphconv_kernel<<<8192, 256, 0, stream>>>(x, filters, g);
  gru_fc_kernel<<<256, 256, 0, stream>>>(g, w_ih, w_hh, b_ih, b_hh,
                                         fc_w, fc_b, out);
}

// Round 5
// 660.467 us; speedup vs baseline: 17.6338x; 1.5899x over previous
//
#include <hip/hip_runtime.h>
#include <hip/hip_bf16.h>

typedef float f32x4 __attribute__((ext_vector_type(4)));
typedef short bf16x8 __attribute__((ext_vector_type(8)));

__device__ __forceinline__ float sigmoidf_(float x) {
  return 1.0f / (1.0f + expf(-x));
}

__device__ __forceinline__ short f2bf(float f) {
  union { float f; unsigned u; } v; v.f = f;
  return (short)((v.u + 0x7FFFu + ((v.u >> 16) & 1u)) >> 16);
}

#define FMA4(ACC, S, V)                                                        \
  ACC.x += (S) * (V).x; ACC.y += (S) * (V).y;                                  \
  ACC.z += (S) * (V).z; ACC.w += (S) * (V).w;

#define DOT4(ACC, AV, CV)                                                      \
  ACC += (AV).x * (CV).x; ACC += (AV).y * (CV).y;                              \
  ACC += (AV).z * (CV).z; ACC += (AV).w * (CV).w;

// ---------------------------------------------------------------------------
// Kernel 1: per-(b,l) patch graph conv.  grid = 8192, block = 256.
// (unchanged from round 3 — known good, ~471 us)
// ---------------------------------------------------------------------------
__global__ __launch_bounds__(256, 3) void graphconv_kernel(
    const float* __restrict__ x,        // (256, 64, 2048)
    const float* __restrict__ filters,  // (3, 64, 64)
    float* __restrict__ g)              // (16384, 2048)
{
  __shared__ float A[64][68];                 // xf / Tx2
  __shared__ float B[64][68];                 // Gram / sim / Tx1
  __shared__ float F[64 * 64];                // current filter (linear)
  __shared__ float adjw[64][8];
  __shared__ unsigned long long adjp[64];     // 8 packed byte-indices per row
  __shared__ float sq[64];

  const int tid = threadIdx.x;
  const int m  = blockIdx.x;
  const int bb = m >> 5;
  const int l  = m & 31;

  {
    const int s  = tid >> 2;
    const int c0 = (tid & 3) * 16;
    const float* src = x + ((size_t)bb * 64 + s) * 2048 + l * 64 + c0;
    const float4 v0 = *(const float4*)(src + 0);
    const float4 v1 = *(const float4*)(src + 4);
    const float4 v2 = *(const float4*)(src + 8);
    const float4 v3 = *(const float4*)(src + 12);
    *(float4*)&A[s][c0 + 0]  = v0;
    *(float4*)&A[s][c0 + 4]  = v1;
    *(float4*)&A[s][c0 + 8]  = v2;
    *(float4*)&A[s][c0 + 12] = v3;
  }
  __syncthreads();

  const int pn = tid >> 4;   // 0..15
  const int pk = tid & 15;   // 0..15
  const int h0 = pk * 4;

  {
    float4 acc0 = {0.f,0.f,0.f,0.f}, acc1 = acc0, acc2 = acc0, acc3 = acc0;
    #pragma unroll 4
    for (int ch = 0; ch < 16; ++ch) {
      const float4 av0 = *(const float4*)&A[pn +  0][ch * 4];
      const float4 av1 = *(const float4*)&A[pn + 16][ch * 4];
      const float4 av2 = *(const float4*)&A[pn + 32][ch * 4];
      const float4 av3 = *(const float4*)&A[pn + 48][ch * 4];
      const float4 cv0 = *(const float4*)&A[pk +  0][ch * 4];
      const float4 cv1 = *(const float4*)&A[pk + 16][ch * 4];
      const float4 cv2 = *(const float4*)&A[pk + 32][ch * 4];
      const float4 cv3 = *(const float4*)&A[pk + 48][ch * 4];
      DOT4(acc0.x, av0, cv0) DOT4(acc0.y, av0, cv1)
      DOT4(acc0.z, av0, cv2) DOT4(acc0.w, av0, cv3)
      DOT4(acc1.x, av1, cv0) DOT4(acc1.y, av1, cv1)
      DOT4(acc1.z, av1, cv2) DOT4(acc1.w, av1, cv3)
      DOT4(acc2.x, av2, cv0) DOT4(acc2.y, av2, cv1)
      DOT4(acc2.z, av2, cv2) DOT4(acc2.w, av2, cv3)
      DOT4(acc3.x, av3, cv0) DOT4(acc3.y, av3, cv1)
      DOT4(acc3.z, av3, cv2) DOT4(acc3.w, av3, cv3)
    }
    B[pn +  0][pk +  0] = acc0.x; B[pn +  0][pk + 16] = acc0.y;
    B[pn +  0][pk + 32] = acc0.z; B[pn +  0][pk + 48] = acc0.w;
    B[pn + 16][pk +  0] = acc1.x; B[pn + 16][pk + 16] = acc1.y;
    B[pn + 16][pk + 32] = acc1.z; B[pn + 16][pk + 48] = acc1.w;
    B[pn + 32][pk +  0] = acc2.x; B[pn + 32][pk + 16] = acc2.y;
    B[pn + 32][pk + 32] = acc2.z; B[pn + 32][pk + 48] = acc2.w;
    B[pn + 48][pk +  0] = acc3.x; B[pn + 48][pk + 16] = acc3.y;
    B[pn + 48][pk + 32] = acc3.z; B[pn + 48][pk + 48] = acc3.w;
  }
  __syncthreads();
  if (tid < 64) sq[tid] = B[tid][tid];
  __syncthreads();

  #pragma unroll
  for (int it = 0; it < 4; ++it) {
    const int e  = tid + it * 256;
    const int n  = e & 63;
    const int pc = e >> 6;
    float4 v = *(const float4*)&B[n][pc * 4];
    const float sn_ = sq[n];
    v.x = expf(-fmaxf(sn_ + sq[pc * 4 + 0] - 2.0f * v.x, 0.0f));
    v.y = expf(-fmaxf(sn_ + sq[pc * 4 + 1] - 2.0f * v.y, 0.0f));
    v.z = expf(-fmaxf(sn_ + sq[pc * 4 + 2] - 2.0f * v.z, 0.0f));
    v.w = expf(-fmaxf(sn_ + sq[pc * 4 + 3] - 2.0f * v.w, 0.0f));
    *(float4*)&B[n][pc * 4] = v;
  }
  __syncthreads();

#define INSERT(CV, CI)                                                        \
  {                                                                           \
    float cv = (CV); int ci = (CI);                                           \
    _Pragma("unroll")                                                         \
    for (int s_ = 0; s_ < 8; ++s_) {                                          \
      const bool bt = cv > lv[s_];                                            \
      const float tv = lv[s_]; const int ti = li[s_];                         \
      lv[s_] = bt ? cv : tv;  li[s_] = bt ? ci : ti;                          \
      cv     = bt ? tv : cv;  ci     = bt ? ti : ci;                          \
    }                                                                         \
  }
  if (tid < 64) {
    float lv[8]; int li[8];
    #pragma unroll
    for (int j = 0; j < 8; ++j) { lv[j] = -1.0f; li[j] = 0; }
    #pragma unroll 4
    for (int pc = 0; pc < 16; ++pc) {
      const float4 v = *(const float4*)&B[tid][pc * 4];
      INSERT(v.x, pc * 4 + 0)
      INSERT(v.y, pc * 4 + 1)
      INSERT(v.z, pc * 4 + 2)
      INSERT(v.w, pc * 4 + 3)
    }
    unsigned long long p = 0ull;
    #pragma unroll
    for (int j = 0; j < 8; ++j) {
      adjw[tid][j] = lv[j];
      p |= ((unsigned long long)(unsigned)li[j]) << (8 * j);
    }
    adjp[tid] = p;
  } else {
    for (int e = tid - 64; e < 1024; e += 192)
      ((float4*)F)[e] = ((const float4*)filters)[e];
  }
  __syncthreads();

  float4 facc0 = {0.f,0.f,0.f,0.f}, facc1 = facc0, facc2 = facc0, facc3 = facc0;

#define GEMM_PHASE(TILE)                                                      \
  {                                                                           \
    _Pragma("unroll 4")                                                       \
    for (int ch = 0; ch < 16; ++ch) {                                         \
      const float4 av0 = *(const float4*)&TILE[pn +  0][ch * 4];              \
      const float4 av1 = *(const float4*)&TILE[pn + 16][ch * 4];              \
      const float4 av2 = *(const float4*)&TILE[pn + 32][ch * 4];              \
      const float4 av3 = *(const float4*)&TILE[pn + 48][ch * 4];              \
      const float4 f0 = *(const float4*)(F + (ch * 4 + 0) * 64 + h0);         \
      const float4 f1 = *(const float4*)(F + (ch * 4 + 1) * 64 + h0);         \
      const float4 f2 = *(const float4*)(F + (ch * 4 + 2) * 64 + h0);         \
      const float4 f3 = *(const float4*)(F + (ch * 4 + 3) * 64 + h0);         \
      FMA4(facc0, av0.x, f0) FMA4(facc0, av0.y, f1)                           \
      FMA4(facc0, av0.z, f2) FMA4(facc0, av0.w, f3)                           \
      FMA4(facc1, av1.x, f0) FMA4(facc1, av1.y, f1)                           \
      FMA4(facc1, av1.z, f2) FMA4(facc1, av1.w, f3)                           \
      FMA4(facc2, av2.x, f0) FMA4(facc2, av2.y, f1)                           \
      FMA4(facc2, av2.z, f2) FMA4(facc2, av2.w, f3)                           \
      FMA4(facc3, av3.x, f0) FMA4(facc3, av3.y, f1)                           \
      FMA4(facc3, av3.z, f2) FMA4(facc3, av3.w, f3)                           \
    }                                                                         \
  }

  const int sn = tid >> 2;
  const int jb = (tid & 3) * 16;

#define SPARSE_GATHER(SRC)                                                    \
  {                                                                           \
    const unsigned long long p_ = adjp[sn];                                   \
    _Pragma("unroll")                                                         \
    for (int s_ = 0; s_ < 8; ++s_) {                                          \
      const float w_ = adjw[sn][s_];                                          \
      const int kk_ = (int)((p_ >> (8 * s_)) & 63);                           \
      const float4 q0 = *(const float4*)&SRC[kk_][jb + 0];                    \
      const float4 q1 = *(const float4*)&SRC[kk_][jb + 4];                    \
      const float4 q2 = *(const float4*)&SRC[kk_][jb + 8];                    \
      const float4 q3 = *(const float4*)&SRC[kk_][jb + 12];                   \
      FMA4(o0, w_, q0) FMA4(o1, w_, q1) FMA4(o2, w_, q2) FMA4(o3, w_, q3)     \
    }                                                                         \
  }

  GEMM_PHASE(A)
  __syncthreads();
  {
    for (int e = tid; e < 1024; e += 256)
      ((float4*)F)[e] = ((const float4*)(filters + 4096))[e];
    float4 o0 = {0.f,0.f,0.f,0.f}, o1 = o0, o2 = o0, o3 = o0;
    SPARSE_GATHER(A)
    *(float4*)&B[sn][jb + 0]  = o0;
    *(float4*)&B[sn][jb + 4]  = o1;
    *(float4*)&B[sn][jb + 8]  = o2;
    *(float4*)&B[sn][jb + 12] = o3;
  }
  __syncthreads();
  GEMM_PHASE(B)
  __syncthreads();
  {
    for (int e = tid; e < 1024; e += 256)
      ((float4*)F)[e] = ((const float4*)(filters + 8192))[e];
    float4 o0 = {0.f,0.f,0.f,0.f}, o1 = o0, o2 = o0, o3 = o0;
    SPARSE_GATHER(B)
    const float4 t0 = *(const float4*)&A[sn][jb + 0];
    const float4 t1 = *(const float4*)&A[sn][jb + 4];
    const float4 t2 = *(const float4*)&A[sn][jb + 8];
    const float4 t3 = *(const float4*)&A[sn][jb + 12];
    float4 r0, r1, r2, r3;
    r0.x = 2.0f*o0.x - t0.x; r0.y = 2.0f*o0.y - t0.y;
    r0.z = 2.0f*o0.z - t0.z; r0.w = 2.0f*o0.w - t0.w;
    r1.x = 2.0f*o1.x - t1.x; r1.y = 2.0f*o1.y - t1.y;
    r1.z = 2.0f*o1.z - t1.z; r1.w = 2.0f*o1.w - t1.w;
    r2.x = 2.0f*o2.x - t2.x; r2.y = 2.0f*o2.y - t2.y;
    r2.z = 2.0f*o2.z - t2.z; r2.w = 2.0f*o2.w - t2.w;
    r3.x = 2.0f*o3.x - t3.x; r3.y = 2.0f*o3.y - t3.y;
    r3.z = 2.0f*o3.z - t3.z; r3.w = 2.0f*o3.w - t3.w;
    *(float4*)&A[sn][jb + 0]  = r0;
    *(float4*)&A[sn][jb + 4]  = r1;
    *(float4*)&A[sn][jb + 8]  = r2;
    *(float4*)&A[sn][jb + 12] = r3;
  }
  __syncthreads();
  GEMM_PHASE(A)

  *(float4*)(g + ((size_t)(bb * 64 + pn +  0)) * 2048 + l * 64 + h0) = facc0;
  *(float4*)(g + ((size_t)(bb * 64 + pn + 16)) * 2048 + l * 64 + h0) = facc1;
  *(float4*)(g + ((size_t)(bb * 64 + pn + 32)) * 2048 + l * 64 + h0) = facc2;
  *(float4*)(g + ((size_t)(bb * 64 + pn + 48)) * 2048 + l * 64 + h0) = facc3;
}

// ---------------------------------------------------------------------------
// Kernel 2: GRU (32 steps) + fused FC via bf16 MFMA.
// grid = 256 (one batch/block), block = 512 (8 waves).
// Wave w = (m-tile = w&3: seqs 16m..16m+15, n-half jp = w>>2: h-cols 32jp..+31).
// Weights live in registers as B-fragments (24 frags).
// fc_w is indexed by LOCAL node n (0..63): n*2048 + l*64 + h.
// mfma_f32_16x16x32_bf16 layouts (verified, learn_hip m89):
//   A: row = lane&15,  k = 8*(lane>>4) + e   (e = 0..7)
//   B: col = lane&15,  k = 8*(lane>>4) + e
//   D: col = lane&15,  row = 4*(lane>>4) + reg
// ---------------------------------------------------------------------------
__global__ __launch_bounds__(512, 2) void gru_fc_kernel(
    const float* __restrict__ gg,    // (16384, 2048) seq-major
    const float* __restrict__ w_ih,  // (192, 64)
    const float* __restrict__ w_hh,  // (192, 64)
    const float* __restrict__ b_ih,
    const float* __restrict__ b_hh,
    const float* __restrict__ fc_w,  // (131072) = n*2048 + l*64 + h  (n local!)
    const float* __restrict__ fc_b,
    float* __restrict__ out)         // (256)
{
  __shared__ short Xp[2][64][72];    // bf16 xt, double-buffered
  __shared__ short Hp[64][72];       // bf16 h
  __shared__ float FCW[2][64][68];   // fp32 fc_w slice, double-buffered
  __shared__ float red[8];

  const int tid  = threadIdx.x;
  const int blk  = blockIdx.x;
  const int lane = tid & 63;
  const int w    = tid >> 6;   // 0..7
  const int mt   = w & 3;      // seq tile
  const int jp   = w >> 2;     // n half
  const int lg   = lane >> 4;  // 0..3
  const int lc   = lane & 15;

  // ---- weight B-frags -> registers (one-time) ----
  bf16x8 wfi[3][2][2], wfh[3][2][2];   // [gate][jj][kstep]
  #pragma unroll
  for (int g3 = 0; g3 < 3; ++g3) {
    #pragma unroll
    for (int jj = 0; jj < 2; ++jj) {
      const int row = 64 * g3 + 32 * jp + 16 * jj + lc;
      #pragma unroll
      for (int s = 0; s < 2; ++s) {
        const float* pi = w_ih + row * 64 + 32 * s + 8 * lg;
        const float* ph = w_hh + row * 64 + 32 * s + 8 * lg;
        const float4 a0 = *(const float4*)(pi);
        const float4 a1 = *(const float4*)(pi + 4);
        const float4 c0 = *(const float4*)(ph);
        const float4 c1 = *(const float4*)(ph + 4);
        bf16x8 fi, fh;
        fi[0] = f2bf(a0.x); fi[1] = f2bf(a0.y); fi[2] = f2bf(a0.z);
        fi[3] = f2bf(a0.w); fi[4] = f2bf(a1.x); fi[5] = f2bf(a1.y);
        fi[6] = f2bf(a1.z); fi[7] = f2bf(a1.w);
        fh[0] = f2bf(c0.x); fh[1] = f2bf(c0.y); fh[2] = f2bf(c0.z);
        fh[3] = f2bf(c0.w); fh[4] = f2bf(c1.x); fh[5] = f2bf(c1.y);
        fh[6] = f2bf(c1.z); fh[7] = f2bf(c1.w);
        wfi[g3][jj][s] = fi;
        wfh[g3][jj][s] = fh;
      }
    }
  }
  // ---- biases (per-lane, by h position) ----
  float br_[2], bz_[2], bni[2], bnh[2];
  #pragma unroll
  for (int jj = 0; jj < 2; ++jj) {
    const int h = 32 * jp + 16 * jj + lc;
    br_[jj] = b_ih[h] + b_hh[h];
    bz_[jj] = b_ih[64 + h] + b_hh[64 + h];
    bni[jj] = b_ih[128 + h];
    bnh[jj] = b_hh[128 + h];
  }

  // ---- init: zero Hp, stage Xp[0] & FCW[0] ----
  for (int e = tid; e < 64 * 72; e += 512) ((short*)Hp)[e] = 0;
  const int srow = tid >> 3;
  const int sc   = (tid & 7) * 8;
  {
    const float* src = gg + ((size_t)(blk * 64 + srow)) * 2048 + sc;
    const float4 u0 = *(const float4*)(src);
    const float4 u1 = *(const float4*)(src + 4);
    bf16x8 px;
    px[0] = f2bf(u0.x); px[1] = f2bf(u0.y); px[2] = f2bf(u0.z);
    px[3] = f2bf(u0.w); px[4] = f2bf(u1.x); px[5] = f2bf(u1.y);
    px[6] = f2bf(u1.z); px[7] = f2bf(u1.w);
    *(bf16x8*)&Xp[0][srow][sc] = px;
    const float* fsrc = fc_w + (size_t)srow * 2048 + sc;   // l = 0, LOCAL n
    *(float4*)&FCW[0][srow][sc]     = *(const float4*)(fsrc);
    *(float4*)&FCW[0][srow][sc + 4] = *(const float4*)(fsrc + 4);
  }
  __syncthreads();

  float hprev[2][4] = {};   // [jj][r] fp32 recurrence state
  float fcp = 0.0f;
  int cur = 0;

  const int arow = 16 * mt + lc;   // A-frag row in Xp/Hp

  for (int l = 0; l < 32; ++l) {
    // prefetch next-step staging into registers
    float4 nx0, nx1, nf0, nf1;
    if (l + 1 < 32) {
      const float* src = gg + ((size_t)(blk * 64 + srow)) * 2048
                         + (l + 1) * 64 + sc;
      nx0 = *(const float4*)(src);
      nx1 = *(const float4*)(src + 4);
      const float* fsrc = fc_w + (size_t)srow * 2048 + (l + 1) * 64 + sc;
      nf0 = *(const float4*)(fsrc);
      nf1 = *(const float4*)(fsrc + 4);
    }

    // ---- A-frags from LDS ----
    const bf16x8 ax0 = *(const bf16x8*)&Xp[cur][arow][8 * lg];
    const bf16x8 ax1 = *(const bf16x8*)&Xp[cur][arow][32 + 8 * lg];
    const bf16x8 ah0 = *(const bf16x8*)&Hp[arow][8 * lg];
    const bf16x8 ah1 = *(const bf16x8*)&Hp[arow][32 + 8 * lg];

    // ---- 24 MFMA: gi[g][jj], gh[g][jj] ----
    f32x4 gi[3][2], gh[3][2];
    #pragma unroll
    for (int g3 = 0; g3 < 3; ++g3) {
      #pragma unroll
      for (int jj = 0; jj < 2; ++jj) {
        f32x4 z4 = {0.f, 0.f, 0.f, 0.f};
        f32x4 t = __builtin_amdgcn_mfma_f32_16x16x32_bf16(
            ax0, wfi[g3][jj][0], z4, 0, 0, 0);
        gi[g3][jj] = __builtin_amdgcn_mfma_f32_16x16x32_bf16(
            ax1, wfi[g3][jj][1], t, 0, 0, 0);
        f32x4 u = __builtin_amdgcn_mfma_f32_16x16x32_bf16(
            ah0, wfh[g3][jj][0], z4, 0, 0, 0);
        gh[g3][jj] = __builtin_amdgcn_mfma_f32_16x16x32_bf16(
            ah1, wfh[g3][jj][1], u, 0, 0, 0);
      }
    }

    // ---- pointwise (fully in-register) ----
    short hbf[2][4];
    #pragma unroll
    for (int jj = 0; jj < 2; ++jj) {
      const int h = 32 * jp + 16 * jj + lc;
      #pragma unroll
      for (int r = 0; r < 4; ++r) {
        const int seq = 16 * mt + 4 * lg + r;
        const float rr = sigmoidf_(gi[0][jj][r] + gh[0][jj][r] + br_[jj]);
        const float zz = sigmoidf_(gi[1][jj][r] + gh[1][jj][r] + bz_[jj]);
        const float nn = tanhf(gi[2][jj][r] + bni[jj]
                               + rr * (gh[2][jj][r] + bnh[jj]));
        const float hv = (1.0f - zz) * nn + zz * hprev[jj][r];
        hprev[jj][r] = hv;
        fcp += hv * FCW[cur][seq][h];
        hbf[jj][r] = f2bf(hv);
      }
    }
    __syncthreads();   // all reads of Xp[cur]/Hp/FCW[cur] complete

    // ---- writes: h -> Hp (bf16), next X/FCW staging ----
    #pragma unroll
    for (int jj = 0; jj < 2; ++jj) {
      #pragma unroll
      for (int r = 0; r < 4; ++r)
        Hp[16 * mt + 4 * lg + r][32 * jp + 16 * jj + lc] = hbf[jj][r];
    }
    if (l + 1 < 32) {
      bf16x8 px;
      px[0] = f2bf(nx0.x); px[1] = f2bf(nx0.y); px[2] = f2bf(nx0.z);
      px[3] = f2bf(nx0.w); px[4] = f2bf(nx1.x); px[5] = f2bf(nx1.y);
      px[6] = f2bf(nx1.z); px[7] = f2bf(nx1.w);
      *(bf16x8*)&Xp[cur ^ 1][srow][sc] = px;
      *(float4*)&FCW[cur ^ 1][srow][sc]     = nf0;
      *(float4*)&FCW[cur ^ 1][srow][sc + 4] = nf1;
    }
    cur ^= 1;
    __syncthreads();   // writes visible
  }

  // ---- FC reduce: wave sums -> red[8] -> out[blk] ----
  float v = fcp;
  v += __shfl_xor(v, 1);  v += __shfl_xor(v, 2);
  v += __shfl_xor(v, 4);  v += __shfl_xor(v, 8);
  v += __shfl_xor(v, 16); v += __shfl_xor(v, 32);
  if (lane == 0) red[w] = v;
  __syncthreads();
  if (tid == 0) {
    float s = red[0] + red[1] + red[2] + red[3]
            + red[4] + red[5] + red[6] + red[7];
    out[blk] = s + fc_b[0];
  }
}

// ---------------------------------------------------------------------------
extern "C" void kernel_launch(void* const* d_in, const int* in_sizes, int n_in,
                              void* d_out, int out_size, void* d_ws, size_t ws_size,
                              hipStream_t stream) {
  (void)in_sizes; (void)n_in; (void)out_size; (void)ws_size;
  const float* x       = (const float*)d_in[0];
  const float* filters = (const float*)d_in[1];
  const float* w_ih    = (const float*)d_in[2];
  const float* w_hh    = (const float*)d_in[3];
  const float* b_ih    = (const float*)d_in[4];
  const float* b_hh    = (const float*)d_in[5];
  const float* fc_w    = (const float*)d_in[6];
  const float* fc_b    = (const float*)d_in[7];
  float* out = (float*)d_out;
  float* g   = (float*)d_ws;   // 16384*2048 f32 = 134 MB

  graphconv_kernel<<<8192, 256, 0, stream>>>(x, filters, g);
  gru_fc_kernel<<<256, 512, 0, stream>>>(g, w_ih, w_hh, b_ih, b_hh,
                                         fc_w, fc_b, out);
}